// Round 3
// baseline (154.659 us; speedup 1.0000x reference)
//
#include <hip/hip_runtime.h>

#define N_NODES 50000
#define N_EDGES 625000
#define DIM 128
#define RCAP 16           // slots per (node, xcd) sub-bucket
#define OCAP 64           // global overflow slots per node (~never used)

typedef __bf16 bf16x8 __attribute__((ext_vector_type(8)));
typedef __bf16 bf16x4 __attribute__((ext_vector_type(4)));
typedef __bf16 bf16x2 __attribute__((ext_vector_type(2)));
typedef float f32x4 __attribute__((ext_vector_type(4)));

__device__ __forceinline__ float bflo(unsigned u) { return __uint_as_float(u << 16); }
__device__ __forceinline__ float bfhi(unsigned u) { return __uint_as_float(u & 0xffff0000u); }

// ===========================================================================
// K1: fused [GEMM1 | XCD-local bucket-CSR fill].
// R3 delta: cnt/bucket are partitioned per physical XCD (s_getreg XCC_ID).
// Counter lines + bucket lines in region x are touched ONLY by XCD x ->
// atomics/stores execute in the local L2 with no cross-XCD line bouncing
// (R2 showed the fill is contention-bound, not latency-bound).
// Region overflow (>16 edges of one node via one XCD, ~never) spills to a
// global overflow bucket so correctness holds under ANY block->XCD mapping.
// ===========================================================================
__global__ __launch_bounds__(512) void gemm1_fill_k(
    const float* __restrict__ A_f32,
    const float* __restrict__ W,
    const float* __restrict__ bias,
    __bf16* __restrict__ out_bf16,
    const int* __restrict__ src,
    const int* __restrict__ dst,
    int* __restrict__ cnt9,          // [8][N] region counters + [8*N..] overflow counters
    int* __restrict__ bucket,        // [8][N][RCAP]
    int* __restrict__ obucket,       // [N][OCAP]
    const float* __restrict__ W_phy,
    __bf16* __restrict__ Wb,
    int gemm_blocks)
{
    const int t = threadIdx.x;

    if ((int)blockIdx.x >= gemm_blocks) {
        if ((int)blockIdx.x == gemm_blocks) {
            if (t < 16) {
                bf16x8 z = {};
                *(bf16x8*)&out_bf16[(size_t)N_NODES * DIM + t * 8] = z;
            }
            for (int i = t; i < 4096; i += 512) {
                float4 f = ((const float4*)W_phy)[i];
                bf16x4 pk = { (__bf16)f.x, (__bf16)f.y, (__bf16)f.z, (__bf16)f.w };
                *(bf16x4*)&Wb[i * 4] = pk;
            }
        }
        int xcd;
        asm volatile("s_getreg_b32 %0, hwreg(HW_REG_XCC_ID)" : "=s"(xcd));
        xcd &= 7;
        const int cb = xcd * N_NODES;

        int idx = ((int)blockIdx.x - gemm_blocks) * 512 + t;
        if (idx < N_EDGES / 8) {                        // 625000 = 8 * 78125
            int4 sa = ((const int4*)src)[idx * 2];
            int4 sb = ((const int4*)src)[idx * 2 + 1];
            int4 da = ((const int4*)dst)[idx * 2];
            int4 db = ((const int4*)dst)[idx * 2 + 1];
            // all returning atomics issued back-to-back (XCD-local lines)
            int p0 = atomicAdd(&cnt9[cb + da.x], 1);
            int p1 = atomicAdd(&cnt9[cb + da.y], 1);
            int p2 = atomicAdd(&cnt9[cb + da.z], 1);
            int p3 = atomicAdd(&cnt9[cb + da.w], 1);
            int p4 = atomicAdd(&cnt9[cb + db.x], 1);
            int p5 = atomicAdd(&cnt9[cb + db.y], 1);
            int p6 = atomicAdd(&cnt9[cb + db.z], 1);
            int p7 = atomicAdd(&cnt9[cb + db.w], 1);
            // XCD-local scattered stores (one 64B line per (node,region))
            if (p0 < RCAP) bucket[((cb + da.x) << 4) + p0] = sa.x;
            else { int q = atomicAdd(&cnt9[8 * N_NODES + da.x], 1); obucket[(da.x << 6) + q] = sa.x; }
            if (p1 < RCAP) bucket[((cb + da.y) << 4) + p1] = sa.y;
            else { int q = atomicAdd(&cnt9[8 * N_NODES + da.y], 1); obucket[(da.y << 6) + q] = sa.y; }
            if (p2 < RCAP) bucket[((cb + da.z) << 4) + p2] = sa.z;
            else { int q = atomicAdd(&cnt9[8 * N_NODES + da.z], 1); obucket[(da.z << 6) + q] = sa.z; }
            if (p3 < RCAP) bucket[((cb + da.w) << 4) + p3] = sa.w;
            else { int q = atomicAdd(&cnt9[8 * N_NODES + da.w], 1); obucket[(da.w << 6) + q] = sa.w; }
            if (p4 < RCAP) bucket[((cb + db.x) << 4) + p4] = sb.x;
            else { int q = atomicAdd(&cnt9[8 * N_NODES + db.x], 1); obucket[(db.x << 6) + q] = sb.x; }
            if (p5 < RCAP) bucket[((cb + db.y) << 4) + p5] = sb.y;
            else { int q = atomicAdd(&cnt9[8 * N_NODES + db.y], 1); obucket[(db.y << 6) + q] = sb.y; }
            if (p6 < RCAP) bucket[((cb + db.z) << 4) + p6] = sb.z;
            else { int q = atomicAdd(&cnt9[8 * N_NODES + db.z], 1); obucket[(db.z << 6) + q] = sb.z; }
            if (p7 < RCAP) bucket[((cb + db.w) << 4) + p7] = sb.w;
            else { int q = atomicAdd(&cnt9[8 * N_NODES + db.w], 1); obucket[(db.w << 6) + q] = sb.w; }
        }
        return;
    }

    __shared__ __align__(16) __bf16 w_lds[128 * 136];   // 34.8 KB

    for (int i = t; i < 4096; i += 512) {               // 8 iters
        float4 f = ((const float4*)W)[i];
        int n = i >> 5;
        int k = (i & 31) << 2;
        bf16x4 pk = { (__bf16)f.x, (__bf16)f.y, (__bf16)f.z, (__bf16)f.w };
        *(bf16x4*)&w_lds[n * 136 + k] = pk;             // ds_write_b64
    }
    __syncthreads();

    const int wave = t >> 6;           // 0..7
    const int lane = t & 63;
    const int q = lane >> 4;
    const int mr = lane & 15;

    const int m0 = blockIdx.x * 128 + wave * 16;
    int arow = m0 + mr;
    if (arow >= N_NODES) arow = N_NODES - 1;

    f32x4 acc[8] = {};

#pragma unroll
    for (int ks = 0; ks < 4; ++ks) {
        const int k0 = ks * 32 + q * 8;
        const float4* ap = (const float4*)&A_f32[(size_t)arow * DIM + k0];
        float4 a0 = ap[0], a1 = ap[1];
        bf16x8 af;
        af[0] = (__bf16)a0.x; af[1] = (__bf16)a0.y;
        af[2] = (__bf16)a0.z; af[3] = (__bf16)a0.w;
        af[4] = (__bf16)a1.x; af[5] = (__bf16)a1.y;
        af[6] = (__bf16)a1.z; af[7] = (__bf16)a1.w;
#pragma unroll
        for (int nt = 0; nt < 8; ++nt) {
            bf16x8 bfr = *(const bf16x8*)&w_lds[(nt * 16 + mr) * 136 + k0];
            acc[nt] = __builtin_amdgcn_mfma_f32_16x16x32_bf16(af, bfr, acc[nt], 0, 0, 0);
        }
    }

    __syncthreads();                   // all w_lds reads done
    float* lds_f = (float*)w_lds;      // 64 x 132 fp32 buffer
    const int nb = blockIdx.x * 128;

#pragma unroll
    for (int half = 0; half < 2; ++half) {
        if ((wave >> 2) == half) {
            int lw = wave & 3;
#pragma unroll
            for (int nt = 0; nt < 8; ++nt)
#pragma unroll
                for (int r = 0; r < 4; ++r)
                    lds_f[(lw * 16 + q * 4 + r) * 132 + nt * 16 + mr] = acc[nt][r];
        }
        __syncthreads();
        for (int i = t; i < 2048; i += 512) {
            int lr = i >> 5;
            int cg = (i & 31) << 2;
            int grow = nb + half * 64 + lr;
            if (grow < N_NODES) {
                float4 v = *(const float4*)&lds_f[lr * 132 + cg];
                float4 b4 = *(const float4*)&bias[cg];
                bf16x4 o;
                o[0] = (__bf16)fmaxf(v.x + b4.x, 0.f);
                o[1] = (__bf16)fmaxf(v.y + b4.y, 0.f);
                o[2] = (__bf16)fmaxf(v.z + b4.z, 0.f);
                o[3] = (__bf16)fmaxf(v.w + b4.w, 0.f);
                *(bf16x4*)&out_bf16[(size_t)grow * DIM + cg] = o;
            }
        }
        __syncthreads();
    }
}

// ===========================================================================
// K2+K3 FUSED. R3 delta: per-node gather list is rebuilt from the 8
// XCD-local sub-buckets -- 2 lane-parallel slot loads + ballot/popcount
// compaction into a per-wave LDS index list, then the proven batch-8 gather.
// Node-level loads are 2-deep software-pipelined. MFMA GEMM2 unchanged.
// ===========================================================================
__global__ __launch_bounds__(512, 4) void agg_gemm2_k(
    const __bf16* __restrict__ h,
    const int* __restrict__ cnt9,
    const int* __restrict__ bucket,
    const int* __restrict__ obucket,
    const float* __restrict__ eps_p,
    const __bf16* __restrict__ Wb,
    const float* __restrict__ bias,
    float* __restrict__ out)
{
    __shared__ __align__(16) __bf16 lds[2 * 128 * 136];   // 69.6 KB: [W | A]
    __shared__ __align__(16) int widx_all[8][200];        // 6.4 KB gather lists
    __bf16* const w_lds = lds;
    __bf16* const a_lds = lds + 128 * 136;

    const int t = threadIdx.x;

    // ---- stage W tile (issued first; drains under the aggregation phase) ----
    for (int i = t; i < 2048; i += 512) {               // 4 iters, b128 copy
        int n = i >> 4;
        int kk = (i & 15) << 3;
        bf16x8 v = *(const bf16x8*)&Wb[n * DIM + kk];
        *(bf16x8*)&w_lds[n * 136 + kk] = v;
    }

    const int wave = t >> 6;
    const int lane = t & 63;
    const int ch = lane << 1;                           // 2 channels per lane
    const int xq = lane >> 4;                           // region quad 0..3
    const int sj = lane & 15;                           // slot within region
    const int rowbase = __builtin_amdgcn_readfirstlane(blockIdx.x * 128 + wave * 16);
    const float eps = eps_p[0];
    int* const widx = widx_all[wave];

    // 2-deep pipelined per-node loads
    int ndv[2], cAv[2], cBv[2], rAv[2], rBv[2], ocv[2];
    unsigned svv[2];
    auto nload = [&](int sl, int ii) {
        const int node = rowbase + ii;
        const int nd = (node < N_NODES) ? node : (N_NODES - 1);
        ndv[sl] = nd;
        int ca = cnt9[xq * N_NODES + nd];
        int cb = cnt9[(xq + 4) * N_NODES + nd];
        cAv[sl] = (ca < RCAP) ? ca : RCAP;
        cBv[sl] = (cb < RCAP) ? cb : RCAP;
        rAv[sl] = bucket[((xq * N_NODES + nd) << 4) + sj];
        rBv[sl] = bucket[(((xq + 4) * N_NODES + nd) << 4) + sj];
        ocv[sl] = cnt9[8 * N_NODES + nd];
        svv[sl] = *(const unsigned*)&h[(size_t)nd * DIM + ch];
    };
    nload(0, 0);

#pragma unroll
    for (int i = 0; i < 16; ++i) {
        if (i < 15) nload((i + 1) & 1, i + 1);
        const int sl = i & 1;
        const int nd = ndv[sl];

        // ---- compact the 8 sub-lists into widx[0..deg) ----
        const unsigned long long mA = __ballot(sj < cAv[sl]);
        const unsigned long long mB = __ballot(sj < cBv[sl]);
        const unsigned long long below = (1ull << lane) - 1ull;
        const int tA = __popcll(mA);
        int deg = tA + __popcll(mB);
        if (sj < cAv[sl]) widx[__popcll(mA & below)] = rAv[sl];
        if (sj < cBv[sl]) widx[tA + __popcll(mB & below)] = rBv[sl];
        const int oc = ocv[sl];
        if (oc > 0) {                                   // ~never taken
            if (lane < oc) widx[deg + lane] = obucket[(nd << 6) + lane];
            deg += oc;
        }
        if (lane < 8) widx[deg + lane] = N_NODES;       // zero-row pad for batch-8

        // ---- batch-8 gather (indices broadcast from LDS) ----
        float ax = 0.f, ay = 0.f;
        for (int e = 0; e < deg; e += 8) {
            int4 w0 = *(const int4*)&widx[e];
            int4 w1 = *(const int4*)&widx[e + 4];
            unsigned v0 = *(const unsigned*)&h[(size_t)w0.x * DIM + ch];
            unsigned v1 = *(const unsigned*)&h[(size_t)w0.y * DIM + ch];
            unsigned v2 = *(const unsigned*)&h[(size_t)w0.z * DIM + ch];
            unsigned v3 = *(const unsigned*)&h[(size_t)w0.w * DIM + ch];
            unsigned v4 = *(const unsigned*)&h[(size_t)w1.x * DIM + ch];
            unsigned v5 = *(const unsigned*)&h[(size_t)w1.y * DIM + ch];
            unsigned v6 = *(const unsigned*)&h[(size_t)w1.z * DIM + ch];
            unsigned v7 = *(const unsigned*)&h[(size_t)w1.w * DIM + ch];
            ax += (bflo(v0) + bflo(v1)) + (bflo(v2) + bflo(v3))
                + (bflo(v4) + bflo(v5)) + (bflo(v6) + bflo(v7));
            ay += (bfhi(v0) + bfhi(v1)) + (bfhi(v2) + bfhi(v3))
                + (bfhi(v4) + bfhi(v5)) + (bfhi(v6) + bfhi(v7));
        }
        ax = 1.0f + eps * bflo(svv[sl]) + ax;
        ay = 1.0f + eps * bfhi(svv[sl]) + ay;
        bf16x2 o; o[0] = (__bf16)ax; o[1] = (__bf16)ay;
        *(bf16x2*)&a_lds[(wave * 16 + i) * 136 + ch] = o;   // own-wave row
    }

    __syncthreads();            // W tile staged by all waves; A rows are own-wave

    const int q = lane >> 4;
    const int mr = lane & 15;

    f32x4 acc[8] = {};

#pragma unroll
    for (int ks = 0; ks < 4; ++ks) {
        const int k0 = ks * 32 + q * 8;
        bf16x8 af = *(const bf16x8*)&a_lds[(wave * 16 + mr) * 136 + k0];
#pragma unroll
        for (int nt = 0; nt < 8; ++nt) {
            bf16x8 bfr = *(const bf16x8*)&w_lds[(nt * 16 + mr) * 136 + k0];
            acc[nt] = __builtin_amdgcn_mfma_f32_16x16x32_bf16(af, bfr, acc[nt], 0, 0, 0);
        }
    }

    __syncthreads();                   // all w_lds/a_lds reads done
    float* lds_f = (float*)lds;        // reuse W half: 64 x 132 fp32
    const int nb = blockIdx.x * 128;

#pragma unroll
    for (int half = 0; half < 2; ++half) {
        if ((wave >> 2) == half) {
            int lw = wave & 3;
#pragma unroll
            for (int nt = 0; nt < 8; ++nt)
#pragma unroll
                for (int r = 0; r < 4; ++r)
                    lds_f[(lw * 16 + q * 4 + r) * 132 + nt * 16 + mr] = acc[nt][r];
        }
        __syncthreads();
        for (int i2 = t; i2 < 2048; i2 += 512) {
            int lr = i2 >> 5;
            int cg = (i2 & 31) << 2;
            int grow = nb + half * 64 + lr;
            if (grow < N_NODES) {
                float4 v = *(const float4*)&lds_f[lr * 132 + cg];
                float4 b4 = *(const float4*)&bias[cg];
                v.x = fmaxf(v.x + b4.x, 0.f);
                v.y = fmaxf(v.y + b4.y, 0.f);
                v.z = fmaxf(v.z + b4.z, 0.f);
                v.w = fmaxf(v.w + b4.w, 0.f);
                *(float4*)&out[(size_t)grow * DIM + cg] = v;
            }
        }
        __syncthreads();
    }
}

extern "C" void kernel_launch(void* const* d_in, const int* in_sizes, int n_in,
                              void* d_out, int out_size, void* d_ws, size_t ws_size,
                              hipStream_t stream) {
    const float* feats = (const float*)d_in[0];
    const int*   src   = (const int*)d_in[1];
    const int*   dst   = (const int*)d_in[2];
    const float* W_f   = (const float*)d_in[3];
    const float* b_f   = (const float*)d_in[4];
    const float* W_phy = (const float*)d_in[5];
    const float* b_phy = (const float*)d_in[6];
    const float* eps   = (const float*)d_in[7];
    float* out = (float*)d_out;

    const size_t HN = (size_t)(N_NODES + 1) * DIM;      // +1 zero row
    __bf16* h    = (__bf16*)d_ws;                                   // 12.8 MB
    int* bucket  = (int*)(h + HN);                                  // 8*N*16 = 25.6 MB
    int* obucket = bucket + (size_t)8 * N_NODES * RCAP;             // N*64 = 12.8 MB
    int* cnt9    = obucket + (size_t)N_NODES * OCAP;                // 9*N = 1.8 MB
    __bf16* Wb   = (__bf16*)(cnt9 + (size_t)9 * N_NODES);           // 32 KB

    const int gblocks = (N_NODES + 127) / 128;          // 391 (K1 gemm part)
    const int fblocks = (N_EDGES / 8 + 511) / 512;      // 153 (K1 fill part)

    hipMemsetAsync(cnt9, 0, (size_t)9 * N_NODES * sizeof(int), stream);

    gemm1_fill_k<<<gblocks + fblocks, 512, 0, stream>>>(
        feats, W_f, b_f, h, src, dst, cnt9, bucket, obucket, W_phy, Wb, gblocks);

    agg_gemm2_k<<<gblocks, 512, 0, stream>>>(
        h, cnt9, bucket, obucket, eps, Wb, b_phy, out);
}

// Round 5
// 152.315 us; speedup vs baseline: 1.0154x; 1.0154x over previous
//
#include <hip/hip_runtime.h>

#define N_NODES 50000
#define N_EDGES 625000
#define DIM 128
#define RCAP 16           // slots per (node, xcd) sub-bucket
#define OCAP 64           // global overflow slots per node (~never used)

typedef __bf16 bf16x8 __attribute__((ext_vector_type(8)));
typedef __bf16 bf16x4 __attribute__((ext_vector_type(4)));
typedef __bf16 bf16x2 __attribute__((ext_vector_type(2)));
typedef float f32x4 __attribute__((ext_vector_type(4)));

__device__ __forceinline__ float bflo(unsigned u) { return __uint_as_float(u << 16); }
__device__ __forceinline__ float bfhi(unsigned u) { return __uint_as_float(u & 0xffff0000u); }

// XCD-local (workgroup-scope) returning atomic: executes as a local-L2 TCC
// RMW instead of a fabric-serialized agent-scope RMW. Legal ONLY because
// each cnt9 region is touched by exactly one XCD (R3 layout).
__device__ __forceinline__ int at_wg(int* p) {
    return __hip_atomic_fetch_add(p, 1, __ATOMIC_RELAXED, __HIP_MEMORY_SCOPE_WORKGROUP);
}

// ===========================================================================
// K1: fused [GEMM1 | XCD-local bucket-CSR fill].
// R5 = R4 resubmit (R4 bench was an infra failure, theory untested):
// region-counter atomics demoted agent->workgroup scope (local L2 RMW).
// R2/R3 proved the fill is neither latency- nor address-locality-bound; the
// remaining common factor across all 42us variants is agent-scope atomic
// serialization at the chip coherence point. Overflow counters (cross-XCD)
// keep agent scope.
// ===========================================================================
__global__ __launch_bounds__(512) void gemm1_fill_k(
    const float* __restrict__ A_f32,
    const float* __restrict__ W,
    const float* __restrict__ bias,
    __bf16* __restrict__ out_bf16,
    const int* __restrict__ src,
    const int* __restrict__ dst,
    int* __restrict__ cnt9,          // [8][N] region counters + [8*N..] overflow counters
    int* __restrict__ bucket,        // [8][N][RCAP]
    int* __restrict__ obucket,       // [N][OCAP]
    const float* __restrict__ W_phy,
    __bf16* __restrict__ Wb,
    int gemm_blocks)
{
    const int t = threadIdx.x;

    if ((int)blockIdx.x >= gemm_blocks) {
        if ((int)blockIdx.x == gemm_blocks) {
            if (t < 16) {
                bf16x8 z = {};
                *(bf16x8*)&out_bf16[(size_t)N_NODES * DIM + t * 8] = z;
            }
            for (int i = t; i < 4096; i += 512) {
                float4 f = ((const float4*)W_phy)[i];
                bf16x4 pk = { (__bf16)f.x, (__bf16)f.y, (__bf16)f.z, (__bf16)f.w };
                *(bf16x4*)&Wb[i * 4] = pk;
            }
        }
        int xcd;
        asm volatile("s_getreg_b32 %0, hwreg(HW_REG_XCC_ID)" : "=s"(xcd));
        xcd &= 7;
        const int cb = xcd * N_NODES;

        int idx = ((int)blockIdx.x - gemm_blocks) * 512 + t;
        if (idx < N_EDGES / 8) {                        // 625000 = 8 * 78125
            int4 sa = ((const int4*)src)[idx * 2];
            int4 sb = ((const int4*)src)[idx * 2 + 1];
            int4 da = ((const int4*)dst)[idx * 2];
            int4 db = ((const int4*)dst)[idx * 2 + 1];
            // all returning atomics issued back-to-back, XCD-local L2 RMW
            int p0 = at_wg(&cnt9[cb + da.x]);
            int p1 = at_wg(&cnt9[cb + da.y]);
            int p2 = at_wg(&cnt9[cb + da.z]);
            int p3 = at_wg(&cnt9[cb + da.w]);
            int p4 = at_wg(&cnt9[cb + db.x]);
            int p5 = at_wg(&cnt9[cb + db.y]);
            int p6 = at_wg(&cnt9[cb + db.z]);
            int p7 = at_wg(&cnt9[cb + db.w]);
            // XCD-local scattered stores (one 64B line per (node,region))
            if (p0 < RCAP) bucket[((cb + da.x) << 4) + p0] = sa.x;
            else { int q = atomicAdd(&cnt9[8 * N_NODES + da.x], 1); obucket[(da.x << 6) + q] = sa.x; }
            if (p1 < RCAP) bucket[((cb + da.y) << 4) + p1] = sa.y;
            else { int q = atomicAdd(&cnt9[8 * N_NODES + da.y], 1); obucket[(da.y << 6) + q] = sa.y; }
            if (p2 < RCAP) bucket[((cb + da.z) << 4) + p2] = sa.z;
            else { int q = atomicAdd(&cnt9[8 * N_NODES + da.z], 1); obucket[(da.z << 6) + q] = sa.z; }
            if (p3 < RCAP) bucket[((cb + da.w) << 4) + p3] = sa.w;
            else { int q = atomicAdd(&cnt9[8 * N_NODES + da.w], 1); obucket[(da.w << 6) + q] = sa.w; }
            if (p4 < RCAP) bucket[((cb + db.x) << 4) + p4] = sb.x;
            else { int q = atomicAdd(&cnt9[8 * N_NODES + db.x], 1); obucket[(db.x << 6) + q] = sb.x; }
            if (p5 < RCAP) bucket[((cb + db.y) << 4) + p5] = sb.y;
            else { int q = atomicAdd(&cnt9[8 * N_NODES + db.y], 1); obucket[(db.y << 6) + q] = sb.y; }
            if (p6 < RCAP) bucket[((cb + db.z) << 4) + p6] = sb.z;
            else { int q = atomicAdd(&cnt9[8 * N_NODES + db.z], 1); obucket[(db.z << 6) + q] = sb.z; }
            if (p7 < RCAP) bucket[((cb + db.w) << 4) + p7] = sb.w;
            else { int q = atomicAdd(&cnt9[8 * N_NODES + db.w], 1); obucket[(db.w << 6) + q] = sb.w; }
        }
        return;
    }

    __shared__ __align__(16) __bf16 w_lds[128 * 136];   // 34.8 KB

    for (int i = t; i < 4096; i += 512) {               // 8 iters
        float4 f = ((const float4*)W)[i];
        int n = i >> 5;
        int k = (i & 31) << 2;
        bf16x4 pk = { (__bf16)f.x, (__bf16)f.y, (__bf16)f.z, (__bf16)f.w };
        *(bf16x4*)&w_lds[n * 136 + k] = pk;             // ds_write_b64
    }
    __syncthreads();

    const int wave = t >> 6;           // 0..7
    const int lane = t & 63;
    const int q = lane >> 4;
    const int mr = lane & 15;

    const int m0 = blockIdx.x * 128 + wave * 16;
    int arow = m0 + mr;
    if (arow >= N_NODES) arow = N_NODES - 1;

    f32x4 acc[8] = {};

#pragma unroll
    for (int ks = 0; ks < 4; ++ks) {
        const int k0 = ks * 32 + q * 8;
        const float4* ap = (const float4*)&A_f32[(size_t)arow * DIM + k0];
        float4 a0 = ap[0], a1 = ap[1];
        bf16x8 af;
        af[0] = (__bf16)a0.x; af[1] = (__bf16)a0.y;
        af[2] = (__bf16)a0.z; af[3] = (__bf16)a0.w;
        af[4] = (__bf16)a1.x; af[5] = (__bf16)a1.y;
        af[6] = (__bf16)a1.z; af[7] = (__bf16)a1.w;
#pragma unroll
        for (int nt = 0; nt < 8; ++nt) {
            bf16x8 bfr = *(const bf16x8*)&w_lds[(nt * 16 + mr) * 136 + k0];
            acc[nt] = __builtin_amdgcn_mfma_f32_16x16x32_bf16(af, bfr, acc[nt], 0, 0, 0);
        }
    }

    __syncthreads();                   // all w_lds reads done
    float* lds_f = (float*)w_lds;      // 64 x 132 fp32 buffer
    const int nb = blockIdx.x * 128;

#pragma unroll
    for (int half = 0; half < 2; ++half) {
        if ((wave >> 2) == half) {
            int lw = wave & 3;
#pragma unroll
            for (int nt = 0; nt < 8; ++nt)
#pragma unroll
                for (int r = 0; r < 4; ++r)
                    lds_f[(lw * 16 + q * 4 + r) * 132 + nt * 16 + mr] = acc[nt][r];
        }
        __syncthreads();
        for (int i = t; i < 2048; i += 512) {
            int lr = i >> 5;
            int cg = (i & 31) << 2;
            int grow = nb + half * 64 + lr;
            if (grow < N_NODES) {
                float4 v = *(const float4*)&lds_f[lr * 132 + cg];
                float4 b4 = *(const float4*)&bias[cg];
                bf16x4 o;
                o[0] = (__bf16)fmaxf(v.x + b4.x, 0.f);
                o[1] = (__bf16)fmaxf(v.y + b4.y, 0.f);
                o[2] = (__bf16)fmaxf(v.z + b4.z, 0.f);
                o[3] = (__bf16)fmaxf(v.w + b4.w, 0.f);
                *(bf16x4*)&out_bf16[(size_t)grow * DIM + cg] = o;
            }
        }
        __syncthreads();
    }
}

// ===========================================================================
// K2+K3 FUSED (R3 structure, unchanged): gather lists rebuilt from the 8
// XCD-local sub-buckets via ballot/popcount compaction, 2-deep pipelined
// node loads, batch-8 gather, MFMA GEMM2 + bias + relu.
// ===========================================================================
__global__ __launch_bounds__(512, 4) void agg_gemm2_k(
    const __bf16* __restrict__ h,
    const int* __restrict__ cnt9,
    const int* __restrict__ bucket,
    const int* __restrict__ obucket,
    const float* __restrict__ eps_p,
    const __bf16* __restrict__ Wb,
    const float* __restrict__ bias,
    float* __restrict__ out)
{
    __shared__ __align__(16) __bf16 lds[2 * 128 * 136];   // 69.6 KB: [W | A]
    __shared__ __align__(16) int widx_all[8][200];        // 6.4 KB gather lists
    __bf16* const w_lds = lds;
    __bf16* const a_lds = lds + 128 * 136;

    const int t = threadIdx.x;

    // ---- stage W tile (issued first; drains under the aggregation phase) ----
    for (int i = t; i < 2048; i += 512) {               // 4 iters, b128 copy
        int n = i >> 4;
        int kk = (i & 15) << 3;
        bf16x8 v = *(const bf16x8*)&Wb[n * DIM + kk];
        *(bf16x8*)&w_lds[n * 136 + kk] = v;
    }

    const int wave = t >> 6;
    const int lane = t & 63;
    const int ch = lane << 1;                           // 2 channels per lane
    const int xq = lane >> 4;                           // region quad 0..3
    const int sj = lane & 15;                           // slot within region
    const int rowbase = __builtin_amdgcn_readfirstlane(blockIdx.x * 128 + wave * 16);
    const float eps = eps_p[0];
    int* const widx = widx_all[wave];

    // 2-deep pipelined per-node loads
    int ndv[2], cAv[2], cBv[2], rAv[2], rBv[2], ocv[2];
    unsigned svv[2];
    auto nload = [&](int sl, int ii) {
        const int node = rowbase + ii;
        const int nd = (node < N_NODES) ? node : (N_NODES - 1);
        ndv[sl] = nd;
        int ca = cnt9[xq * N_NODES + nd];
        int cb = cnt9[(xq + 4) * N_NODES + nd];
        cAv[sl] = (ca < RCAP) ? ca : RCAP;
        cBv[sl] = (cb < RCAP) ? cb : RCAP;
        rAv[sl] = bucket[((xq * N_NODES + nd) << 4) + sj];
        rBv[sl] = bucket[(((xq + 4) * N_NODES + nd) << 4) + sj];
        ocv[sl] = cnt9[8 * N_NODES + nd];
        svv[sl] = *(const unsigned*)&h[(size_t)nd * DIM + ch];
    };
    nload(0, 0);

#pragma unroll
    for (int i = 0; i < 16; ++i) {
        if (i < 15) nload((i + 1) & 1, i + 1);
        const int sl = i & 1;
        const int nd = ndv[sl];

        // ---- compact the 8 sub-lists into widx[0..deg) ----
        const unsigned long long mA = __ballot(sj < cAv[sl]);
        const unsigned long long mB = __ballot(sj < cBv[sl]);
        const unsigned long long below = (1ull << lane) - 1ull;
        const int tA = __popcll(mA);
        int deg = tA + __popcll(mB);
        if (sj < cAv[sl]) widx[__popcll(mA & below)] = rAv[sl];
        if (sj < cBv[sl]) widx[tA + __popcll(mB & below)] = rBv[sl];
        const int oc = ocv[sl];
        if (oc > 0) {                                   // ~never taken
            if (lane < oc) widx[deg + lane] = obucket[(nd << 6) + lane];
            deg += oc;
        }
        if (lane < 8) widx[deg + lane] = N_NODES;       // zero-row pad for batch-8

        // ---- batch-8 gather (indices broadcast from LDS) ----
        float ax = 0.f, ay = 0.f;
        for (int e = 0; e < deg; e += 8) {
            int4 w0 = *(const int4*)&widx[e];
            int4 w1 = *(const int4*)&widx[e + 4];
            unsigned v0 = *(const unsigned*)&h[(size_t)w0.x * DIM + ch];
            unsigned v1 = *(const unsigned*)&h[(size_t)w0.y * DIM + ch];
            unsigned v2 = *(const unsigned*)&h[(size_t)w0.z * DIM + ch];
            unsigned v3 = *(const unsigned*)&h[(size_t)w0.w * DIM + ch];
            unsigned v4 = *(const unsigned*)&h[(size_t)w1.x * DIM + ch];
            unsigned v5 = *(const unsigned*)&h[(size_t)w1.y * DIM + ch];
            unsigned v6 = *(const unsigned*)&h[(size_t)w1.z * DIM + ch];
            unsigned v7 = *(const unsigned*)&h[(size_t)w1.w * DIM + ch];
            ax += (bflo(v0) + bflo(v1)) + (bflo(v2) + bflo(v3))
                + (bflo(v4) + bflo(v5)) + (bflo(v6) + bflo(v7));
            ay += (bfhi(v0) + bfhi(v1)) + (bfhi(v2) + bfhi(v3))
                + (bfhi(v4) + bfhi(v5)) + (bfhi(v6) + bfhi(v7));
        }
        ax = 1.0f + eps * bflo(svv[sl]) + ax;
        ay = 1.0f + eps * bfhi(svv[sl]) + ay;
        bf16x2 o; o[0] = (__bf16)ax; o[1] = (__bf16)ay;
        *(bf16x2*)&a_lds[(wave * 16 + i) * 136 + ch] = o;   // own-wave row
    }

    __syncthreads();            // W tile staged by all waves; A rows are own-wave

    const int q = lane >> 4;
    const int mr = lane & 15;

    f32x4 acc[8] = {};

#pragma unroll
    for (int ks = 0; ks < 4; ++ks) {
        const int k0 = ks * 32 + q * 8;
        bf16x8 af = *(const bf16x8*)&a_lds[(wave * 16 + mr) * 136 + k0];
#pragma unroll
        for (int nt = 0; nt < 8; ++nt) {
            bf16x8 bfr = *(const bf16x8*)&w_lds[(nt * 16 + mr) * 136 + k0];
            acc[nt] = __builtin_amdgcn_mfma_f32_16x16x32_bf16(af, bfr, acc[nt], 0, 0, 0);
        }
    }

    __syncthreads();                   // all w_lds/a_lds reads done
    float* lds_f = (float*)lds;        // reuse W half: 64 x 132 fp32
    const int nb = blockIdx.x * 128;

#pragma unroll
    for (int half = 0; half < 2; ++half) {
        if ((wave >> 2) == half) {
            int lw = wave & 3;
#pragma unroll
            for (int nt = 0; nt < 8; ++nt)
#pragma unroll
                for (int r = 0; r < 4; ++r)
                    lds_f[(lw * 16 + q * 4 + r) * 132 + nt * 16 + mr] = acc[nt][r];
        }
        __syncthreads();
        for (int i2 = t; i2 < 2048; i2 += 512) {
            int lr = i2 >> 5;
            int cg = (i2 & 31) << 2;
            int grow = nb + half * 64 + lr;
            if (grow < N_NODES) {
                float4 v = *(const float4*)&lds_f[lr * 132 + cg];
                float4 b4 = *(const float4*)&bias[cg];
                v.x = fmaxf(v.x + b4.x, 0.f);
                v.y = fmaxf(v.y + b4.y, 0.f);
                v.z = fmaxf(v.z + b4.z, 0.f);
                v.w = fmaxf(v.w + b4.w, 0.f);
                *(float4*)&out[(size_t)grow * DIM + cg] = v;
            }
        }
        __syncthreads();
    }
}

extern "C" void kernel_launch(void* const* d_in, const int* in_sizes, int n_in,
                              void* d_out, int out_size, void* d_ws, size_t ws_size,
                              hipStream_t stream) {
    const float* feats = (const float*)d_in[0];
    const int*   src   = (const int*)d_in[1];
    const int*   dst   = (const int*)d_in[2];
    const float* W_f   = (const float*)d_in[3];
    const float* b_f   = (const float*)d_in[4];
    const float* W_phy = (const float*)d_in[5];
    const float* b_phy = (const float*)d_in[6];
    const float* eps   = (const float*)d_in[7];
    float* out = (float*)d_out;

    const size_t HN = (size_t)(N_NODES + 1) * DIM;      // +1 zero row
    __bf16* h    = (__bf16*)d_ws;                                   // 12.8 MB
    int* bucket  = (int*)(h + HN);                                  // 8*N*16 = 25.6 MB
    int* obucket = bucket + (size_t)8 * N_NODES * RCAP;             // N*64 = 12.8 MB
    int* cnt9    = obucket + (size_t)N_NODES * OCAP;                // 9*N = 1.8 MB
    __bf16* Wb   = (__bf16*)(cnt9 + (size_t)9 * N_NODES);           // 32 KB

    const int gblocks = (N_NODES + 127) / 128;          // 391 (K1 gemm part)
    const int fblocks = (N_EDGES / 8 + 511) / 512;      // 153 (K1 fill part)

    hipMemsetAsync(cnt9, 0, (size_t)9 * N_NODES * sizeof(int), stream);

    gemm1_fill_k<<<gblocks + fblocks, 512, 0, stream>>>(
        feats, W_f, b_f, h, src, dst, cnt9, bucket, obucket, W_phy, Wb, gblocks);

    agg_gemm2_k<<<gblocks, 512, 0, stream>>>(
        h, cnt9, bucket, obucket, eps, Wb, b_phy, out);
}